// Round 18
// baseline (120.782 us; speedup 1.0000x reference)
//
#include <hip/hip_runtime.h>
#include <hip/hip_bf16.h>

typedef __bf16 bf16;
typedef unsigned int u32;
typedef __attribute__((ext_vector_type(4))) float f32x4;
typedef __attribute__((ext_vector_type(16))) float f32x16;
typedef __attribute__((ext_vector_type(8))) bf16 bf16x8;
typedef __attribute__((ext_vector_type(4))) bf16 bf16x4;
typedef __attribute__((ext_vector_type(2))) bf16 bf16x2;
typedef __attribute__((ext_vector_type(4))) u32 u32x4;
typedef __attribute__((ext_vector_type(2))) u32 u32x2;

#define GPTR(p) ((const __attribute__((address_space(1))) u32*)(p))
#define SPTR(p) ((__attribute__((address_space(3))) u32*)(p))

#if __has_builtin(__builtin_amdgcn_permlane32_swap)
#define HAVE_PLSWAP 1
#else
#define HAVE_PLSWAP 0
#endif
#if __has_builtin(__builtin_amdgcn_fdot2_f32_bf16)
#define HAVE_DOT2 1
#else
#define HAVE_DOT2 0
#endif

// Problem constants
constexpr int BATCH = 2, SEQ = 2048, DMODEL = 1024, NH = 16, HD = 64, QKV3 = 3072;
constexpr int MTOK = BATCH * SEQ;  // 4096 tokens

// Workspace layout (bytes)
constexpr size_t OXB = 0;                                       // X bf16 [4096][1024]
constexpr size_t OWQ = OXB + (size_t)MTOK * DMODEL * 2;         // Wqkv^T bf16 [3072][1024]
constexpr size_t OWO = OWQ + (size_t)QKV3 * DMODEL * 2;         // Wout^T bf16 [1024][1024]
constexpr size_t OCS = OWO + (size_t)DMODEL * DMODEL * 2;       // cos/sin f32 [2048][32][2]
constexpr size_t OCQ = OCS + (size_t)SEQ * 32 * 8;              // (hole)
constexpr size_t OQR = OCQ + (size_t)MTOK * QKV3 * 2;           // Q roped [b][h][n][64]
constexpr size_t OKR = OQR + (size_t)BATCH * NH * SEQ * HD * 2; // K roped
constexpr size_t OVT = OKR + (size_t)BATCH * NH * SEQ * HD * 2; // V^T [b][h][64][n]
constexpr size_t OAO = OXB;                                     // attn out (aliases Xb, dead by then)

static __device__ __forceinline__ bf16 tobf(float x) { return (bf16)x; }
static __device__ __forceinline__ float tof(bf16 x) { return (float)x; }

static __device__ __forceinline__ f32x4 mfma16(bf16x8 a, bf16x8 b, f32x4 c) {
  return __builtin_amdgcn_mfma_f32_16x16x32_bf16(a, b, c, 0, 0, 0);
}
static __device__ __forceinline__ f32x16 mfma32(bf16x8 a, bf16x8 b, f32x16 c) {
  return __builtin_amdgcn_mfma_f32_32x32x16_bf16(a, b, c, 0, 0, 0);
}

// ---------------- fused prep kernel (costab | cvt | transW_qkv) ----------
__global__ void k_prep(const float* __restrict__ hs, const float* __restrict__ wqkv,
                       float* __restrict__ cs, bf16* __restrict__ Xb,
                       bf16* __restrict__ Wqkt) {
  __shared__ float tile[32][33];
  int blk = blockIdx.x, tid = threadIdx.x;
  if (blk < 256) {
    int idx = blk * 256 + tid;
    int n = idx >> 5, i = idx & 31;
    float freq = powf(10000.0f, -(float)(2 * i) / 64.0f);
    float ang = (float)n * freq;
    float s, c;
    sincosf(ang, &s, &c);
    cs[idx * 2] = c;
    cs[idx * 2 + 1] = s;
  } else if (blk < 256 + 4096) {
    int i = (blk - 256) * 256 + tid;
    float4 v = ((const float4*)hs)[i];
    bf16x4 o = {tobf(v.x), tobf(v.y), tobf(v.z), tobf(v.w)};
    ((bf16x4*)Xb)[i] = o;
  } else {
    int t = blk - 4352;  // [0, 3072)
    int n0 = (t % 96) * 32, k0 = (t / 96) * 32;
    int tx = tid & 31, ty = tid >> 5;
#pragma unroll
    for (int r = ty; r < 32; r += 8) tile[r][tx] = wqkv[(size_t)(k0 + r) * QKV3 + n0 + tx];
    __syncthreads();
#pragma unroll
    for (int r = ty; r < 32; r += 8) Wqkt[(size_t)(n0 + r) * DMODEL + k0 + tx] = tobf(tile[tx][r]);
  }
}

// ---------------- GEMM2: 64x128 tile, 512 blocks (2/CU, 2 waves/SIMD) --------

__global__ __launch_bounds__(256) void k_gemm2(const bf16* __restrict__ A, const bf16* __restrict__ Bt,
                                               float* __restrict__ C, const float* __restrict__ bias,
                                               int M, int Nn, int K) {
  __shared__ __attribute__((aligned(16))) char smem[36864];  // 3 x (As 4KB | Bs 8KB)
  const int nTn = Nn >> 7;  // 8
  int nwg = gridDim.x;
  int bid = blockIdx.x;
  int wgs = (bid & 7) * (nwg >> 3) + (bid >> 3);  // bijective XCD swizzle (nwg%8==0)
  const int m0 = (wgs / nTn) << 6;
  const int n0 = (wgs % nTn) << 7;
  const int tid = threadIdx.x;
  const int lane = tid & 63, w = tid >> 6;
  const int wr = w >> 1, wc = w & 1;
  const int l15 = lane & 15, lhi = lane >> 4;
  f32x4 acc[2][4] = {};

  const int fA = tid * 16;
  const int rA = fA >> 6;
  const int keA = (((fA & 63) >> 4) ^ ((rA >> 1) & 3)) << 3;
  const int fB0 = tid * 16, fB1 = fB0 + 4096;
  const int rB0 = fB0 >> 6, rB1 = fB1 >> 6;
  const int keB0 = (((fB0 & 63) >> 4) ^ ((rB0 >> 1) & 3)) << 3;
  const int keB1 = (((fB1 & 63) >> 4) ^ ((rB1 >> 1) & 3)) << 3;
  const int rsw = ((l15 >> 1) & 3) << 3;

#define GSTAGE(bb_, k0_)                                                                       \
  do {                                                                                         \
    __builtin_amdgcn_global_load_lds(GPTR(A + (size_t)(m0 + rA) * K + (k0_) + keA),            \
                                     SPTR(smem + (bb_)*12288 + fA), 16, 0, 0);                 \
    __builtin_amdgcn_global_load_lds(GPTR(Bt + (size_t)(n0 + rB0) * K + (k0_) + keB0),         \
                                     SPTR(smem + (bb_)*12288 + 4096 + fB0), 16, 0, 0);         \
    __builtin_amdgcn_global_load_lds(GPTR(Bt + (size_t)(n0 + rB1) * K + (k0_) + keB1),         \
                                     SPTR(smem + (bb_)*12288 + 4096 + fB1), 16, 0, 0);         \
  } while (0)

  GSTAGE(0, 0);
  GSTAGE(1, 32);
  const int nIt = K >> 5;
  int bi = 0, b2 = 2;
  for (int it = 0; it < nIt; ++it) {
    if (it < nIt - 1) {
      asm volatile("s_waitcnt vmcnt(3)" ::: "memory");
    } else {
      asm volatile("s_waitcnt vmcnt(0)" ::: "memory");
    }
    __builtin_amdgcn_s_barrier();
    if (it + 2 < nIt) GSTAGE(b2, (it + 2) << 5);
    const bf16* As = (const bf16*)(smem + bi * 12288);
    const bf16* Bs = (const bf16*)(smem + bi * 12288 + 4096);
    bf16x8 af[2], bfv[4];
#pragma unroll
    for (int i = 0; i < 2; ++i)
      af[i] = *(const bf16x8*)(As + (wr * 32 + i * 16 + l15) * 32 + ((lhi << 3) ^ rsw));
#pragma unroll
    for (int j = 0; j < 4; ++j)
      bfv[j] = *(const bf16x8*)(Bs + (wc * 64 + j * 16 + l15) * 32 + ((lhi << 3) ^ rsw));
    __builtin_amdgcn_s_setprio(1);
#pragma unroll
    for (int i = 0; i < 2; ++i)
#pragma unroll
      for (int j = 0; j < 4; ++j) acc[i][j] = mfma16(af[i], bfv[j], acc[i][j]);
    __builtin_amdgcn_s_setprio(0);
    bi = (bi == 2) ? 0 : bi + 1;
    b2 = (b2 == 2) ? 0 : b2 + 1;
  }
#undef GSTAGE

  float bj[4];
#pragma unroll
  for (int j = 0; j < 4; ++j) bj[j] = bias[n0 + wc * 64 + j * 16 + l15];
#pragma unroll
  for (int i = 0; i < 2; ++i)
#pragma unroll
    for (int j = 0; j < 4; ++j) {
      int row = m0 + wr * 32 + i * 16 + lhi * 4;
      int col = n0 + wc * 64 + j * 16 + l15;
#pragma unroll
      for (int r = 0; r < 4; ++r) C[(size_t)(row + r) * Nn + col] = acc[i][j][r] + bj[j];
    }
}

// ---------------- GEMM1 fused: X x Wqkv^T -> RoPE(Q), RoPE(K), V^T ----------

__global__ __launch_bounds__(256) void k_gemm1f(const bf16* __restrict__ A, const bf16* __restrict__ Bt,
                                                const float* __restrict__ cs,
                                                const float* __restrict__ wout, bf16* __restrict__ Woutt,
                                                bf16* __restrict__ Qr, bf16* __restrict__ Kr,
                                                bf16* __restrict__ Vt) {
  constexpr int K = DMODEL, Nn = QKV3;
  constexpr int NG = (MTOK / 128) * (QKV3 / 128);  // 768 GEMM blocks
  __shared__ __attribute__((aligned(16))) char smem[49152];
  int bid = blockIdx.x;
  const int tid = threadIdx.x;

  if (bid >= NG) {
    float* tile = (float*)smem;  // [32][33]
    int t = bid - NG;            // [0, 1024)
    int n0 = (t & 31) * 32, k0 = (t >> 5) * 32;
    int tx = tid & 31, ty = tid >> 5;
#pragma unroll
    for (int r = ty; r < 32; r += 8) tile[r * 33 + tx] = wout[(size_t)(k0 + r) * DMODEL + n0 + tx];
    __syncthreads();
#pragma unroll
    for (int r = ty; r < 32; r += 8) Woutt[(size_t)(n0 + r) * DMODEL + k0 + tx] = tobf(tile[tx * 33 + r]);
    return;
  }

  const int nTn = Nn >> 7;  // 24
  int wgs = (bid & 7) * (NG >> 3) + (bid >> 3);
  const int m0 = (wgs / nTn) << 7;
  const int n0 = (wgs % nTn) << 7;
  const int lane = tid & 63, w = tid >> 6;
  const int wr = w >> 1, wc = w & 1;
  const int l15 = lane & 15, lhi = lane >> 4;
  f32x4 acc[4][4] = {};

  const int flat0 = w * 1024 + lane * 16;
  const int flat1 = flat0 + 4096;
  const int row0 = flat0 >> 6, row1 = flat1 >> 6;
  const int ke0 = (((flat0 & 63) >> 4) ^ ((row0 >> 1) & 3)) << 3;
  const int ke1 = (((flat1 & 63) >> 4) ^ ((row1 >> 1) & 3)) << 3;
  const int rsw = ((l15 >> 1) & 3) << 3;

#define GSTAGE(bb_, k0_)                                                                       \
  do {                                                                                         \
    __builtin_amdgcn_global_load_lds(GPTR(A + (size_t)(m0 + row0) * K + (k0_) + ke0),          \
                                     SPTR(smem + (bb_)*16384 + flat0), 16, 0, 0);              \
    __builtin_amdgcn_global_load_lds(GPTR(A + (size_t)(m0 + row1) * K + (k0_) + ke1),          \
                                     SPTR(smem + (bb_)*16384 + flat1), 16, 0, 0);              \
    __builtin_amdgcn_global_load_lds(GPTR(Bt + (size_t)(n0 + row0) * K + (k0_) + ke0),         \
                                     SPTR(smem + (bb_)*16384 + 8192 + flat0), 16, 0, 0);       \
    __builtin_amdgcn_global_load_lds(GPTR(Bt + (size_t)(n0 + row1) * K + (k0_) + ke1),         \
                                     SPTR(smem + (bb_)*16384 + 8192 + flat1), 16, 0, 0);       \
  } while (0)

  GSTAGE(0, 0);
  GSTAGE(1, 32);
  const int nIt = K >> 5;  // 32
  int bi = 0, b2 = 2;
  for (int it = 0; it < nIt; ++it) {
    if (it < nIt - 1) {
      asm volatile("s_waitcnt vmcnt(4)" ::: "memory");
    } else {
      asm volatile("s_waitcnt vmcnt(0)" ::: "memory");
    }
    __builtin_amdgcn_s_barrier();
    if (it + 2 < nIt) GSTAGE(b2, (it + 2) << 5);
    const bf16* As = (const bf16*)(smem + bi * 16384);
    const bf16* Bs = (const bf16*)(smem + bi * 16384 + 8192);
    bf16x8 af[4], bfv[4];
#pragma unroll
    for (int i = 0; i < 4; ++i) {
      af[i] = *(const bf16x8*)(As + (wr * 64 + i * 16 + l15) * 32 + ((lhi << 3) ^ rsw));
      bfv[i] = *(const bf16x8*)(Bs + (wc * 64 + i * 16 + l15) * 32 + ((lhi << 3) ^ rsw));
    }
    __builtin_amdgcn_s_setprio(1);
#pragma unroll
    for (int i = 0; i < 4; ++i)
#pragma unroll
      for (int j = 0; j < 4; ++j) acc[i][j] = mfma16(af[i], bfv[j], acc[i][j]);
    __builtin_amdgcn_s_setprio(0);
    bi = (bi == 2) ? 0 : bi + 1;
    b2 = (b2 == 2) ? 0 : b2 + 1;
  }
#undef GSTAGE

  __syncthreads();
  const int part = n0 >> 10;  // 0=q, 1=k, 2=v
  const int b = m0 >> 11;

  if (part < 2) {
    bf16* Cs = (bf16*)smem;  // [128][128]
#pragma unroll
    for (int i = 0; i < 4; ++i)
#pragma unroll
      for (int j = 0; j < 4; ++j) {
        int row = wr * 64 + i * 16 + lhi * 4;
        int col = wc * 64 + j * 16 + l15;
#pragma unroll
        for (int r = 0; r < 4; ++r) Cs[(row + r) * 128 + col] = tobf(acc[i][j][r]);
      }
    __syncthreads();
    bf16* dst = part == 0 ? Qr : Kr;
#pragma unroll
    for (int inst = 0; inst < 8; ++inst) {
      int flat = inst * 4096 + tid * 16;
      int row = flat >> 8, c0 = (flat & 255) >> 1;
      int n = (m0 + row) & 2047;
      int gc = (n0 & 1023) + c0;
      int h = gc >> 6, d0 = gc & 63;
      u32x4 v = *(const u32x4*)(smem + flat);
      const float* cp = cs + (((n << 5) + (d0 >> 1)) << 1);
      f32x4 csA = *(const f32x4*)cp;
      f32x4 csB = *(const f32x4*)(cp + 4);
      u32x4 ow;
#pragma unroll
      for (int j = 0; j < 4; ++j) {
        float cc = (j == 0) ? csA[0] : (j == 1) ? csA[2] : (j == 2) ? csB[0] : csB[2];
        float sn = (j == 0) ? csA[1] : (j == 1) ? csA[3] : (j == 2) ? csB[1] : csB[3];
        u32 pw = v[j];
        u32 tl = pw << 16, th = pw & 0xffff0000u;
        float a0, a1;
        __builtin_memcpy(&a0, &tl, 4);
        __builtin_memcpy(&a1, &th, 4);
        bf16 o0 = tobf(a0 * cc - a1 * sn);
        bf16 o1 = tobf(a1 * cc + a0 * sn);
        unsigned short u0, u1;
        __builtin_memcpy(&u0, &o0, 2);
        __builtin_memcpy(&u1, &o1, 2);
        ow[j] = (u32)u0 | ((u32)u1 << 16);
      }
      *(u32x4*)(dst + (((size_t)(b * 16 + h) * 2048 + n) << 6) + d0) = ow;
    }
  } else {
#pragma unroll
    for (int i = 0; i < 4; ++i)
#pragma unroll
      for (int j = 0; j < 4; ++j) {
        int col = wc * 64 + j * 16 + l15;
#pragma unroll
        for (int r = 0; r < 4; ++r) {
          int row = wr * 64 + i * 16 + lhi * 4 + r;
          int byte = (col << 8) + ((((row >> 3) ^ (col & 7)) << 4) | ((row & 7) << 1));
          *(bf16*)(smem + byte) = tobf(acc[i][j][r]);
        }
      }
    __syncthreads();
#pragma unroll
    for (int inst = 0; inst < 8; ++inst) {
      int flat = inst * 4096 + tid * 16;
      int c = flat >> 8;
      int rr0 = (flat & 255) >> 1;
      u32x4 vv = *(const u32x4*)(smem + (c << 8) + ((((rr0 >> 3) ^ (c & 7)) << 4)));
      int gc = (n0 & 1023) + c;
      int h = gc >> 6, dd = gc & 63;
      *(u32x4*)(Vt + (((size_t)(b * 16 + h) * 64 + dd) << 11) + (m0 & 2047) + rr0) = vv;
    }
  }
}

// ---------------- Flash attention: split-K-4, 16 waves (1024 thr), KBLK=32 --
// Block = 128 q-rows x 4 k-quarter-pipes -> 512 blocks x 16 waves = 8192
// waves = 8 waves/SIMD (if VGPR<=64). Per pipe: K 3x4KB (XOR-swizzled rows,
// counted vmcnt) + V 2x4KB ([64d][32k], 64B rows = 2-way = free) = 20KB;
// 4 pipes = 80KB -> 2 blocks/CU. 16 tiles/pipe (same barrier count as r15,
// half work per tile, 2x the waves). 4-way merge via two LDS phases.
__global__ __launch_bounds__(1024, 4) void k_attn(const bf16* __restrict__ Qr,
                                                  const bf16* __restrict__ Kr,
                                                  const bf16* __restrict__ Vt,
                                                  bf16* __restrict__ AO) {
  __shared__ __attribute__((aligned(16))) char lds[4][20480];  // [pipe][K 12KB | V 8KB]
  // XCD swizzle: 512 blocks, 8 XCDs -> 64 consecutive works per XCD
  int wg = blockIdx.x;
  int work = (wg & 7) * 64 + (wg >> 3);
  int qc = work & 15, h = (work >> 4) & 15, b = work >> 8;
  int tid = threadIdx.x;
  int wv = tid >> 6, lane = tid & 63;
  int pipe = wv >> 2, wsub = wv & 3;
  int l31 = lane & 31, h5 = lane >> 5;
  int q0 = qc * 128 + wsub * 32;
  int kbase = pipe << 9;  // 512 k per pipe
  const bf16* Qb = Qr + ((size_t)(b * NH + h)) * SEQ * 64;
  const bf16* Kb = Kr + ((size_t)(b * NH + h)) * SEQ * 64;
  const bf16* Vb = Vt + ((size_t)(b * NH + h)) * 64 * SEQ;
  char* pb = lds[pipe];

  // staging: 256 threads/pipe x 16B = 4KB tile; 1 K-inst + 1 V-inst each
  int ptid = tid & 255;
  int sf0 = ptid * 16;
  int srk = sf0 >> 7;  // K row 0..31 (128B rows)
  int sck = (sf0 & 127) ^ ((srk & 7) << 4);
  size_t kgb0 = (size_t)srk * 64 + (sck >> 1);
  size_t vgb0 = (size_t)(sf0 >> 6) * SEQ + ((sf0 & 63) >> 1);  // V rows 0..63 (64B)

#define STAGE_K(bi_, kb_)                                                                     \
  do {                                                                                        \
    char* bb_ = pb + (bi_)*4096;                                                              \
    __builtin_amdgcn_global_load_lds(GPTR(Kb + (size_t)(kbase + (kb_)) * 64 + kgb0),          \
                                     SPTR(bb_ + sf0), 16, 0, 0);                              \
  } while (0)
#define STAGE_V(bi_, kb_)                                                                     \
  do {                                                                                        \
    char* bb_ = pb + 12288 + (bi_)*4096;                                                      \
    __builtin_amdgcn_global_load_lds(GPTR(Vb + (size_t)(kbase + (kb_)) + vgb0),               \
                                     SPTR(bb_ + sf0), 16, 0, 0);                              \
  } while (0)

  bf16x8 qf[4];
#pragma unroll
  for (int s = 0; s < 4; ++s) qf[s] = *(const bf16x8*)(Qb + (q0 + l31) * 64 + s * 16 + h5 * 8);

  f32x16 acc0 = {}, acc1 = {};
#if HAVE_DOT2
  float sacc0 = 0.f, sacc1 = 0.f, sacc2 = 0.f, sacc3 = 0.f;
  const bf16x2 ones2 = {(bf16)1.0f, (bf16)1.0f};
#else
  float ssum_run = 0.f;
#endif
  const float sc = 0.125f * 1.44269504f;
  const float FOFF = 8.0f;
  const int sw = (l31 & 7) << 4;
  const int cbase = h5 * 16;

  STAGE_K(0, 0);
  STAGE_V(0, 0);
  STAGE_K(1, 32);

  constexpr int NT = (SEQ / 4) / 32;  // 16 tiles per pipe
  int kc = 0, kc2 = 2;
  for (int t = 0; t < NT; ++t) {
    if (t < NT - 1) {
      asm volatile("s_waitcnt vmcnt(1)" ::: "memory");  // K(t)+V(t) done; K(t+1) flies
    } else {
      asm volatile("s_waitcnt vmcnt(0)" ::: "memory");
    }
    __builtin_amdgcn_s_barrier();
    if (t + 1 < NT) STAGE_V((t + 1) & 1, (t + 1) * 32);
    if (t + 2 < NT) STAGE_K(kc2, (t + 2) * 32);
    char* cbK = pb + kc * 4096;
    char* cbV = pb + 12288 + (t & 1) * 4096;
    kc = (kc == 2) ? 0 : kc + 1;
    kc2 = (kc2 == 2) ? 0 : kc2 + 1;

    // ---- QK^T: S^T[k 0..31][q 0..31] ----
    f32x16 st = {};
    __builtin_amdgcn_s_setprio(1);
#pragma unroll
    for (int s = 0; s < 4; ++s) {
      bf16x8 kf = *(const bf16x8*)(cbK + l31 * 128 + ((s * 32 + cbase) ^ sw));
      st = mfma32(kf, qf[s], st);
    }
    __builtin_amdgcn_s_setprio(0);

    // fused exp2 + bf16 pack
    u32 P32[8];
#pragma unroll
    for (int i = 0; i < 8; ++i) {
      bf16 lo = tobf(__builtin_amdgcn_exp2f(fmaf(st[2 * i], sc, -FOFF)));
      bf16 hi = tobf(__builtin_amdgcn_exp2f(fmaf(st[2 * i + 1], sc, -FOFF)));
      unsigned short ul, uh;
      __builtin_memcpy(&ul, &lo, 2);
      __builtin_memcpy(&uh, &hi, 2);
      P32[i] = (u32)ul | ((u32)uh << 16);
    }

#if HAVE_DOT2
#pragma unroll
    for (int i = 0; i < 8; i += 4) {
      sacc0 = __builtin_amdgcn_fdot2_f32_bf16(__builtin_bit_cast(bf16x2, P32[i]), ones2, sacc0, false);
      sacc1 = __builtin_amdgcn_fdot2_f32_bf16(__builtin_bit_cast(bf16x2, P32[i + 1]), ones2, sacc1, false);
      sacc2 = __builtin_amdgcn_fdot2_f32_bf16(__builtin_bit_cast(bf16x2, P32[i + 2]), ones2, sacc2, false);
      sacc3 = __builtin_amdgcn_fdot2_f32_bf16(__builtin_bit_cast(bf16x2, P32[i + 3]), ones2, sacc3, false);
    }
#else
    {
      float sm[8];
#pragma unroll
      for (int i = 0; i < 8; ++i) {
        u32 ulo = P32[i] << 16, uhi = P32[i] & 0xffff0000u;
        float flo, fhi;
        __builtin_memcpy(&flo, &ulo, 4);
        __builtin_memcpy(&fhi, &uhi, 4);
        sm[i] = flo + fhi;
      }
#pragma unroll
      for (int off = 4; off > 0; off >>= 1)
#pragma unroll
        for (int r = 0; r < off; ++r) sm[r] += sm[r + off];
      ssum_run += sm[0];
    }
#endif

#if !HAVE_PLSWAP
    // h5=0 sends own {2,3,6,7}; h5=1 sends own {0,1,4,5}
    const int sndA[4] = {2, 3, 6, 7};
    const int sndB[4] = {0, 1, 4, 5};
    u32 recv[4];
#pragma unroll
    for (int j = 0; j < 4; ++j) {
      u32 sv = h5 ? P32[sndB[j]] : P32[sndA[j]];
      recv[j] = (u32)__shfl_xor((int)sv, 32, 64);
    }
#endif

    // ---- PV: O^T[d][q] over two 16-k slices ----
    __builtin_amdgcn_s_setprio(1);
#pragma unroll
    for (int s2 = 0; s2 < 2; ++s2) {
      int x0 = s2 * 4;
#if HAVE_PLSWAP
      u32x2 r02 = __builtin_amdgcn_permlane32_swap(P32[x0], P32[x0 + 2], false, false);
      u32x2 r13 = __builtin_amdgcn_permlane32_swap(P32[x0 + 1], P32[x0 + 3], false, false);
      u32x4 wv4 = {r02.x, r13.x, r02.y, r13.y};
#else
      u32 w0 = h5 ? recv[2 * s2] : P32[x0];
      u32 w1 = h5 ? recv[2 * s2 + 1] : P32[x0 + 1];
      u32 w2 = h5 ? P32[x0 + 2] : recv[2 * s2];
      u32 w3 = h5 ? P32[x0 + 3] : recv[2 * s2 + 1];
      u32x4 wv4 = {w0, w1, w2, w3};
#endif
      bf16x8 pfr = __builtin_bit_cast(bf16x8, wv4);
      bf16x8 vf0 = *(const bf16x8*)(cbV + l31 * 64 + s2 * 32 + cbase);
      bf16x8 vf1 = *(const bf16x8*)(cbV + 2048 + l31 * 64 + s2 * 32 + cbase);
      acc0 = mfma32(vf0, pfr, acc0);
      acc1 = mfma32(vf1, pfr, acc1);
    }
    __builtin_amdgcn_s_setprio(0);
  }

#if HAVE_DOT2
  float ssum = (sacc0 + sacc1) + (sacc2 + sacc3);
#else
  float ssum = ssum_run;
#endif

  // ---- 4-way split-K merge (two LDS phases; regions reuse staging LDS) ----
  __syncthreads();
  float* R0 = (float*)&lds[0][0];       // [4 wsub][64 lane][36]
  float* R1 = R0 + 9216;                // second region (36864B each, 73728 total)
  int slot = (wsub * 64 + lane) * 36;
  if (pipe == 1 || pipe == 3) {
    float* R = (pipe == 1) ? R0 : R1;
#pragma unroll
    for (int r = 0; r < 16; r += 4) {
      *(f32x4*)(R + slot + r) = f32x4{acc0[r], acc0[r + 1], acc0[r + 2], acc0[r + 3]};
      *(f32x4*)(R + slot + 16 + r) = f32x4{acc1[r], acc1[r + 1], acc1[r + 2], acc1[r + 3]};
    }
    R[slot + 32] = ssum;
  }
  __syncthreads();
  if (pipe == 0 || pipe == 2) {
    float* R = (pipe == 0) ? R0 : R1;
#pragma unroll
    for (int r = 0; r < 16; r += 4) {
      f32x4 v0 = *(const f32x4*)(R + slot + r);
      f32x4 v1 = *(const f32x4*)(R + slot + 16 + r);
#pragma unroll
      for (int j = 0; j < 4; ++j) { acc0[r + j] += v0[j]; acc1[r + j] += v1[j]; }
    }
    ssum += R[slot + 32];
  }
  __syncthreads();
  if (pipe == 2) {
#pragma unroll
    for (int r = 0; r < 16; r += 4) {
      *(f32x4*)(R0 + slot + r) = f32x4{acc0[r], acc0[r + 1], acc0[r + 2], acc0[r + 3]};
      *(f32x4*)(R0 + slot + 16 + r) = f32x4{acc1[r], acc1[r + 1], acc1[r + 2], acc1[r + 3]};
    }
    R0[slot + 32] = ssum;
  }
  __syncthreads();
  if (pipe == 0) {
#pragma unroll
    for (int r = 0; r < 16; r += 4) {
      f32x4 v0 = *(const f32x4*)(R0 + slot + r);
      f32x4 v1 = *(const f32x4*)(R0 + slot + 16 + r);
#pragma unroll
      for (int j = 0; j < 4; ++j) { acc0[r + j] += v0[j]; acc1[r + j] += v1[j]; }
    }
    ssum += R0[slot + 32];
    ssum += __shfl_xor(ssum, 32, 64);
    float inv = 1.0f / ssum;
    size_t tok = (size_t)(b * SEQ + q0 + l31);
#pragma unroll
    for (int a = 0; a < 4; ++a) {
      bf16x4 ov0, ov1;
#pragma unroll
      for (int j = 0; j < 4; ++j) {
        ov0[j] = tobf(acc0[4 * a + j] * inv);
        ov1[j] = tobf(acc1[4 * a + j] * inv);
      }
      *(bf16x4*)(AO + tok * (NH * HD) + h * 64 + 8 * a + 4 * h5) = ov0;
      *(bf16x4*)(AO + tok * (NH * HD) + h * 64 + 32 + 8 * a + 4 * h5) = ov1;
    }
  }
#undef STAGE_K
#undef STAGE_V
}

// ---------------- launcher ----------------

extern "C" void kernel_launch(void* const* d_in, const int* in_sizes, int n_in,
                              void* d_out, int out_size, void* d_ws, size_t ws_size,
                              hipStream_t stream) {
  const float* hs = (const float*)d_in[0];
  const float* wqkv = (const float*)d_in[1];
  const float* wout = (const float*)d_in[2];
  const float* bout = (const float*)d_in[3];
  char* ws = (char*)d_ws;
  bf16* Xb = (bf16*)(ws + OXB);
  bf16* Wqkt = (bf16*)(ws + OWQ);
  bf16* Woutt = (bf16*)(ws + OWO);
  float* cs = (float*)(ws + OCS);
  bf16* Qr = (bf16*)(ws + OQR);
  bf16* Kr = (bf16*)(ws + OKR);
  bf16* Vt = (bf16*)(ws + OVT);
  bf16* AO = (bf16*)(ws + OAO);

  k_prep<<<7424, 256, 0, stream>>>(hs, wqkv, cs, Xb, Wqkt);
  k_gemm1f<<<(MTOK / 128) * (QKV3 / 128) + 1024, 256, 0, stream>>>(Xb, Wqkt, cs, wout, Woutt, Qr, Kr, Vt);
  k_attn<<<BATCH * NH * (SEQ / 128), 1024, 0, stream>>>(Qr, Kr, Vt, AO);
  k_gemm2<<<(MTOK / 64) * (DMODEL / 128), 256, 0, stream>>>(AO, Woutt, (float*)d_out, bout, MTOK, DMODEL, DMODEL);
}

// Round 19
// 114.893 us; speedup vs baseline: 1.0513x; 1.0513x over previous
//
#include <hip/hip_runtime.h>
#include <hip/hip_bf16.h>

typedef __bf16 bf16;
typedef unsigned int u32;
typedef __attribute__((ext_vector_type(4))) float f32x4;
typedef __attribute__((ext_vector_type(16))) float f32x16;
typedef __attribute__((ext_vector_type(8))) bf16 bf16x8;
typedef __attribute__((ext_vector_type(4))) bf16 bf16x4;
typedef __attribute__((ext_vector_type(2))) bf16 bf16x2;
typedef __attribute__((ext_vector_type(4))) u32 u32x4;
typedef __attribute__((ext_vector_type(2))) u32 u32x2;

#define GPTR(p) ((const __attribute__((address_space(1))) u32*)(p))
#define SPTR(p) ((__attribute__((address_space(3))) u32*)(p))

#if __has_builtin(__builtin_amdgcn_permlane32_swap)
#define HAVE_PLSWAP 1
#else
#define HAVE_PLSWAP 0
#endif
#if __has_builtin(__builtin_amdgcn_fdot2_f32_bf16)
#define HAVE_DOT2 1
#else
#define HAVE_DOT2 0
#endif

// Problem constants
constexpr int BATCH = 2, SEQ = 2048, DMODEL = 1024, NH = 16, HD = 64, QKV3 = 3072;
constexpr int MTOK = BATCH * SEQ;  // 4096 tokens

// Workspace layout (bytes)
constexpr size_t OXB = 0;                                       // X bf16 [4096][1024]
constexpr size_t OWQ = OXB + (size_t)MTOK * DMODEL * 2;         // Wqkv^T bf16 [3072][1024]
constexpr size_t OWO = OWQ + (size_t)QKV3 * DMODEL * 2;         // Wout^T bf16 [1024][1024]
constexpr size_t OCS = OWO + (size_t)DMODEL * DMODEL * 2;       // cos/sin f32 [2048][32][2]
constexpr size_t OCQ = OCS + (size_t)SEQ * 32 * 8;              // (hole)
constexpr size_t OQR = OCQ + (size_t)MTOK * QKV3 * 2;           // Q roped [b][h][n][64]
constexpr size_t OKR = OQR + (size_t)BATCH * NH * SEQ * HD * 2; // K roped
constexpr size_t OVT = OKR + (size_t)BATCH * NH * SEQ * HD * 2; // V^T [b][h][64][n]
constexpr size_t OAO = OXB;                                     // attn out (aliases Xb, dead by then)

static __device__ __forceinline__ bf16 tobf(float x) { return (bf16)x; }
static __device__ __forceinline__ float tof(bf16 x) { return (float)x; }

static __device__ __forceinline__ f32x4 mfma16(bf16x8 a, bf16x8 b, f32x4 c) {
  return __builtin_amdgcn_mfma_f32_16x16x32_bf16(a, b, c, 0, 0, 0);
}
static __device__ __forceinline__ f32x16 mfma32(bf16x8 a, bf16x8 b, f32x16 c) {
  return __builtin_amdgcn_mfma_f32_32x32x16_bf16(a, b, c, 0, 0, 0);
}

// ---------------- fused prep kernel (costab | cvt | transW_qkv) ----------
__global__ void k_prep(const float* __restrict__ hs, const float* __restrict__ wqkv,
                       float* __restrict__ cs, bf16* __restrict__ Xb,
                       bf16* __restrict__ Wqkt) {
  __shared__ float tile[32][33];
  int blk = blockIdx.x, tid = threadIdx.x;
  if (blk < 256) {
    int idx = blk * 256 + tid;
    int n = idx >> 5, i = idx & 31;
    float freq = powf(10000.0f, -(float)(2 * i) / 64.0f);
    float ang = (float)n * freq;
    float s, c;
    sincosf(ang, &s, &c);
    cs[idx * 2] = c;
    cs[idx * 2 + 1] = s;
  } else if (blk < 256 + 4096) {
    int i = (blk - 256) * 256 + tid;
    float4 v = ((const float4*)hs)[i];
    bf16x4 o = {tobf(v.x), tobf(v.y), tobf(v.z), tobf(v.w)};
    ((bf16x4*)Xb)[i] = o;
  } else {
    int t = blk - 4352;  // [0, 3072)
    int n0 = (t % 96) * 32, k0 = (t / 96) * 32;
    int tx = tid & 31, ty = tid >> 5;
#pragma unroll
    for (int r = ty; r < 32; r += 8) tile[r][tx] = wqkv[(size_t)(k0 + r) * QKV3 + n0 + tx];
    __syncthreads();
#pragma unroll
    for (int r = ty; r < 32; r += 8) Wqkt[(size_t)(n0 + r) * DMODEL + k0 + tx] = tobf(tile[tx][r]);
  }
}

// ---------------- GEMM2: 64x128 tile, 512 blocks (2/CU, 2 waves/SIMD) --------
// 3-buffer LDS (12KB each), counted vmcnt(3), XCD-swizzled grid, swizzled LDS.

__global__ __launch_bounds__(256) void k_gemm2(const bf16* __restrict__ A, const bf16* __restrict__ Bt,
                                               float* __restrict__ C, const float* __restrict__ bias,
                                               int M, int Nn, int K) {
  __shared__ __attribute__((aligned(16))) char smem[36864];  // 3 x (As 4KB | Bs 8KB)
  const int nTn = Nn >> 7;  // 8
  int nwg = gridDim.x;
  int bid = blockIdx.x;
  int wgs = (bid & 7) * (nwg >> 3) + (bid >> 3);  // bijective XCD swizzle (nwg%8==0)
  const int m0 = (wgs / nTn) << 6;
  const int n0 = (wgs % nTn) << 7;
  const int tid = threadIdx.x;
  const int lane = tid & 63, w = tid >> 6;
  const int wr = w >> 1, wc = w & 1;
  const int l15 = lane & 15, lhi = lane >> 4;
  f32x4 acc[2][4] = {};

  const int fA = tid * 16;
  const int rA = fA >> 6;
  const int keA = (((fA & 63) >> 4) ^ ((rA >> 1) & 3)) << 3;
  const int fB0 = tid * 16, fB1 = fB0 + 4096;
  const int rB0 = fB0 >> 6, rB1 = fB1 >> 6;
  const int keB0 = (((fB0 & 63) >> 4) ^ ((rB0 >> 1) & 3)) << 3;
  const int keB1 = (((fB1 & 63) >> 4) ^ ((rB1 >> 1) & 3)) << 3;
  const int rsw = ((l15 >> 1) & 3) << 3;

#define GSTAGE(bb_, k0_)                                                                       \
  do {                                                                                         \
    __builtin_amdgcn_global_load_lds(GPTR(A + (size_t)(m0 + rA) * K + (k0_) + keA),            \
                                     SPTR(smem + (bb_)*12288 + fA), 16, 0, 0);                 \
    __builtin_amdgcn_global_load_lds(GPTR(Bt + (size_t)(n0 + rB0) * K + (k0_) + keB0),         \
                                     SPTR(smem + (bb_)*12288 + 4096 + fB0), 16, 0, 0);         \
    __builtin_amdgcn_global_load_lds(GPTR(Bt + (size_t)(n0 + rB1) * K + (k0_) + keB1),         \
                                     SPTR(smem + (bb_)*12288 + 4096 + fB1), 16, 0, 0);         \
  } while (0)

  GSTAGE(0, 0);
  GSTAGE(1, 32);
  const int nIt = K >> 5;
  int bi = 0, b2 = 2;
  for (int it = 0; it < nIt; ++it) {
    if (it < nIt - 1) {
      asm volatile("s_waitcnt vmcnt(3)" ::: "memory");  // tile it done; it+1 in flight
    } else {
      asm volatile("s_waitcnt vmcnt(0)" ::: "memory");
    }
    __builtin_amdgcn_s_barrier();
    if (it + 2 < nIt) GSTAGE(b2, (it + 2) << 5);
    const bf16* As = (const bf16*)(smem + bi * 12288);
    const bf16* Bs = (const bf16*)(smem + bi * 12288 + 4096);
    bf16x8 af[2], bfv[4];
#pragma unroll
    for (int i = 0; i < 2; ++i)
      af[i] = *(const bf16x8*)(As + (wr * 32 + i * 16 + l15) * 32 + ((lhi << 3) ^ rsw));
#pragma unroll
    for (int j = 0; j < 4; ++j)
      bfv[j] = *(const bf16x8*)(Bs + (wc * 64 + j * 16 + l15) * 32 + ((lhi << 3) ^ rsw));
    __builtin_amdgcn_s_setprio(1);
#pragma unroll
    for (int i = 0; i < 2; ++i)
#pragma unroll
      for (int j = 0; j < 4; ++j) acc[i][j] = mfma16(af[i], bfv[j], acc[i][j]);
    __builtin_amdgcn_s_setprio(0);
    bi = (bi == 2) ? 0 : bi + 1;
    b2 = (b2 == 2) ? 0 : b2 + 1;
  }
#undef GSTAGE

  float bj[4];
#pragma unroll
  for (int j = 0; j < 4; ++j) bj[j] = bias[n0 + wc * 64 + j * 16 + l15];
#pragma unroll
  for (int i = 0; i < 2; ++i)
#pragma unroll
    for (int j = 0; j < 4; ++j) {
      int row = m0 + wr * 32 + i * 16 + lhi * 4;
      int col = n0 + wc * 64 + j * 16 + l15;
#pragma unroll
      for (int r = 0; r < 4; ++r) C[(size_t)(row + r) * Nn + col] = acc[i][j][r] + bj[j];
    }
}

// ---------------- GEMM1 fused: X x Wqkv^T -> RoPE(Q), RoPE(K), V^T ----------
// Blocks [0,768): GEMM + fused epilogue. Blocks [768,1792): w_out transpose.

__global__ __launch_bounds__(256) void k_gemm1f(const bf16* __restrict__ A, const bf16* __restrict__ Bt,
                                                const float* __restrict__ cs,
                                                const float* __restrict__ wout, bf16* __restrict__ Woutt,
                                                bf16* __restrict__ Qr, bf16* __restrict__ Kr,
                                                bf16* __restrict__ Vt) {
  constexpr int K = DMODEL, Nn = QKV3;
  constexpr int NG = (MTOK / 128) * (QKV3 / 128);  // 768 GEMM blocks
  __shared__ __attribute__((aligned(16))) char smem[49152];
  int bid = blockIdx.x;
  const int tid = threadIdx.x;

  if (bid >= NG) {
    float* tile = (float*)smem;  // [32][33]
    int t = bid - NG;            // [0, 1024)
    int n0 = (t & 31) * 32, k0 = (t >> 5) * 32;
    int tx = tid & 31, ty = tid >> 5;
#pragma unroll
    for (int r = ty; r < 32; r += 8) tile[r * 33 + tx] = wout[(size_t)(k0 + r) * DMODEL + n0 + tx];
    __syncthreads();
#pragma unroll
    for (int r = ty; r < 32; r += 8) Woutt[(size_t)(n0 + r) * DMODEL + k0 + tx] = tobf(tile[tx * 33 + r]);
    return;
  }

  const int nTn = Nn >> 7;  // 24
  int wgs = (bid & 7) * (NG >> 3) + (bid >> 3);
  const int m0 = (wgs / nTn) << 7;
  const int n0 = (wgs % nTn) << 7;
  const int lane = tid & 63, w = tid >> 6;
  const int wr = w >> 1, wc = w & 1;
  const int l15 = lane & 15, lhi = lane >> 4;
  f32x4 acc[4][4] = {};

  const int flat0 = w * 1024 + lane * 16;
  const int flat1 = flat0 + 4096;
  const int row0 = flat0 >> 6, row1 = flat1 >> 6;
  const int ke0 = (((flat0 & 63) >> 4) ^ ((row0 >> 1) & 3)) << 3;
  const int ke1 = (((flat1 & 63) >> 4) ^ ((row1 >> 1) & 3)) << 3;
  const int rsw = ((l15 >> 1) & 3) << 3;

#define GSTAGE(bb_, k0_)                                                                       \
  do {                                                                                         \
    __builtin_amdgcn_global_load_lds(GPTR(A + (size_t)(m0 + row0) * K + (k0_) + ke0),          \
                                     SPTR(smem + (bb_)*16384 + flat0), 16, 0, 0);              \
    __builtin_amdgcn_global_load_lds(GPTR(A + (size_t)(m0 + row1) * K + (k0_) + ke1),          \
                                     SPTR(smem + (bb_)*16384 + flat1), 16, 0, 0);              \
    __builtin_amdgcn_global_load_lds(GPTR(Bt + (size_t)(n0 + row0) * K + (k0_) + ke0),         \
                                     SPTR(smem + (bb_)*16384 + 8192 + flat0), 16, 0, 0);       \
    __builtin_amdgcn_global_load_lds(GPTR(Bt + (size_t)(n0 + row1) * K + (k0_) + ke1),         \
                                     SPTR(smem + (bb_)*16384 + 8192 + flat1), 16, 0, 0);       \
  } while (0)

  GSTAGE(0, 0);
  GSTAGE(1, 32);
  const int nIt = K >> 5;  // 32
  int bi = 0, b2 = 2;
  for (int it = 0; it < nIt; ++it) {
    if (it < nIt - 1) {
      asm volatile("s_waitcnt vmcnt(4)" ::: "memory");
    } else {
      asm volatile("s_waitcnt vmcnt(0)" ::: "memory");
    }
    __builtin_amdgcn_s_barrier();
    if (it + 2 < nIt) GSTAGE(b2, (it + 2) << 5);
    const bf16* As = (const bf16*)(smem + bi * 16384);
    const bf16* Bs = (const bf16*)(smem + bi * 16384 + 8192);
    bf16x8 af[4], bfv[4];
#pragma unroll
    for (int i = 0; i < 4; ++i) {
      af[i] = *(const bf16x8*)(As + (wr * 64 + i * 16 + l15) * 32 + ((lhi << 3) ^ rsw));
      bfv[i] = *(const bf16x8*)(Bs + (wc * 64 + i * 16 + l15) * 32 + ((lhi << 3) ^ rsw));
    }
    __builtin_amdgcn_s_setprio(1);
#pragma unroll
    for (int i = 0; i < 4; ++i)
#pragma unroll
      for (int j = 0; j < 4; ++j) acc[i][j] = mfma16(af[i], bfv[j], acc[i][j]);
    __builtin_amdgcn_s_setprio(0);
    bi = (bi == 2) ? 0 : bi + 1;
    b2 = (b2 == 2) ? 0 : b2 + 1;
  }
#undef GSTAGE

  __syncthreads();
  const int part = n0 >> 10;  // 0=q, 1=k, 2=v
  const int b = m0 >> 11;

  if (part < 2) {
    bf16* Cs = (bf16*)smem;  // [128][128]
#pragma unroll
    for (int i = 0; i < 4; ++i)
#pragma unroll
      for (int j = 0; j < 4; ++j) {
        int row = wr * 64 + i * 16 + lhi * 4;
        int col = wc * 64 + j * 16 + l15;
#pragma unroll
        for (int r = 0; r < 4; ++r) Cs[(row + r) * 128 + col] = tobf(acc[i][j][r]);
      }
    __syncthreads();
    bf16* dst = part == 0 ? Qr : Kr;
#pragma unroll
    for (int inst = 0; inst < 8; ++inst) {
      int flat = inst * 4096 + tid * 16;
      int row = flat >> 8, c0 = (flat & 255) >> 1;
      int n = (m0 + row) & 2047;
      int gc = (n0 & 1023) + c0;
      int h = gc >> 6, d0 = gc & 63;
      u32x4 v = *(const u32x4*)(smem + flat);
      const float* cp = cs + (((n << 5) + (d0 >> 1)) << 1);
      f32x4 csA = *(const f32x4*)cp;
      f32x4 csB = *(const f32x4*)(cp + 4);
      u32x4 ow;
#pragma unroll
      for (int j = 0; j < 4; ++j) {
        float cc = (j == 0) ? csA[0] : (j == 1) ? csA[2] : (j == 2) ? csB[0] : csB[2];
        float sn = (j == 0) ? csA[1] : (j == 1) ? csA[3] : (j == 2) ? csB[1] : csB[3];
        u32 pw = v[j];
        u32 tl = pw << 16, th = pw & 0xffff0000u;
        float a0, a1;
        __builtin_memcpy(&a0, &tl, 4);
        __builtin_memcpy(&a1, &th, 4);
        bf16 o0 = tobf(a0 * cc - a1 * sn);
        bf16 o1 = tobf(a1 * cc + a0 * sn);
        unsigned short u0, u1;
        __builtin_memcpy(&u0, &o0, 2);
        __builtin_memcpy(&u1, &o1, 2);
        ow[j] = (u32)u0 | ((u32)u1 << 16);
      }
      *(u32x4*)(dst + (((size_t)(b * 16 + h) * 2048 + n) << 6) + d0) = ow;
    }
  } else {
#pragma unroll
    for (int i = 0; i < 4; ++i)
#pragma unroll
      for (int j = 0; j < 4; ++j) {
        int col = wc * 64 + j * 16 + l15;
#pragma unroll
        for (int r = 0; r < 4; ++r) {
          int row = wr * 64 + i * 16 + lhi * 4 + r;
          int byte = (col << 8) + ((((row >> 3) ^ (col & 7)) << 4) | ((row & 7) << 1));
          *(bf16*)(smem + byte) = tobf(acc[i][j][r]);
        }
      }
    __syncthreads();
#pragma unroll
    for (int inst = 0; inst < 8; ++inst) {
      int flat = inst * 4096 + tid * 16;
      int c = flat >> 8;
      int rr0 = (flat & 255) >> 1;
      u32x4 vv = *(const u32x4*)(smem + (c << 8) + ((((rr0 >> 3) ^ (c & 7)) << 4)));
      int gc = (n0 & 1023) + c;
      int h = gc >> 6, dd = gc & 63;
      *(u32x4*)(Vt + (((size_t)(b * 16 + h) * 64 + dd) << 11) + (m0 & 2047) + rr0) = vv;
    }
  }
}

// ---------------- Flash attention (round-15 best: split-K-2, KBLK=64,
// counted-vmcnt K3/V2 pipeline, permlane32_swap, dot2 ssum) ------------------
__global__ __launch_bounds__(512, 4) void k_attn(const bf16* __restrict__ Qr,
                                                 const bf16* __restrict__ Kr,
                                                 const bf16* __restrict__ Vt,
                                                 bf16* __restrict__ AO) {
  __shared__ __attribute__((aligned(16))) char lds[2][40960];
  int wg = blockIdx.x;
  int work = (wg & 7) * 64 + (wg >> 3);
  int qc = work & 15, h = (work >> 4) & 15, b = work >> 8;
  int tid = threadIdx.x;
  int wv = tid >> 6, lane = tid & 63;
  int pipe = wv >> 2, wsub = wv & 3;
  int l31 = lane & 31, h5 = lane >> 5;
  int q0 = qc * 128 + wsub * 32;
  int kbase = pipe << 10;
  const bf16* Qb = Qr + ((size_t)(b * NH + h)) * SEQ * 64;
  const bf16* Kb = Kr + ((size_t)(b * NH + h)) * SEQ * 64;
  const bf16* Vb = Vt + ((size_t)(b * NH + h)) * 64 * SEQ;
  char* pb = lds[pipe];

  int ptid = tid & 255;
  int sf0 = ptid * 16, sf1 = 4096 + ptid * 16;
  int sr0 = sf0 >> 7, sr1 = sf1 >> 7;
  int sc0 = (sf0 & 127) ^ ((sr0 & 7) << 4);
  int sc1 = (sf1 & 127) ^ ((sr1 & 7) << 4);
  size_t kgb0 = (size_t)sr0 * 64 + (sc0 >> 1), kgb1 = (size_t)sr1 * 64 + (sc1 >> 1);
  size_t vgb0 = (size_t)sr0 * SEQ + (sc0 >> 1), vgb1 = (size_t)sr1 * SEQ + (sc1 >> 1);

#define STAGE_K(bi_, kb_)                                                                     \
  do {                                                                                        \
    size_t ko_ = (size_t)(kbase + (kb_));                                                     \
    char* bb_ = pb + (bi_)*8192;                                                              \
    __builtin_amdgcn_global_load_lds(GPTR(Kb + ko_ * 64 + kgb0), SPTR(bb_ + sf0), 16, 0, 0);  \
    __builtin_amdgcn_global_load_lds(GPTR(Kb + ko_ * 64 + kgb1), SPTR(bb_ + sf1), 16, 0, 0);  \
  } while (0)
#define STAGE_V(bi_, kb_)                                                                     \
  do {                                                                                        \
    size_t ko_ = (size_t)(kbase + (kb_));                                                     \
    char* bb_ = pb + 24576 + (bi_)*8192;                                                      \
    __builtin_amdgcn_global_load_lds(GPTR(Vb + ko_ + vgb0), SPTR(bb_ + sf0), 16, 0, 0);       \
    __builtin_amdgcn_global_load_lds(GPTR(Vb + ko_ + vgb1), SPTR(bb_ + sf1), 16, 0, 0);       \
  } while (0)

  bf16x8 qf[4];
#pragma unroll
  for (int s = 0; s < 4; ++s) qf[s] = *(const bf16x8*)(Qb + (q0 + l31) * 64 + s * 16 + h5 * 8);

  f32x16 acc0 = {}, acc1 = {};
#if HAVE_DOT2
  float sacc0 = 0.f, sacc1 = 0.f, sacc2 = 0.f, sacc3 = 0.f;
  const bf16x2 ones2 = {(bf16)1.0f, (bf16)1.0f};
#else
  float ssum_run = 0.f;
#endif
  const float sc = 0.125f * 1.44269504f;
  const float FOFF = 8.0f;
  const int sw = (l31 & 7) << 4;
  const int cbase = h5 * 16;

  STAGE_K(0, 0);
  STAGE_V(0, 0);
  STAGE_K(1, 64);

  constexpr int NT = (SEQ / 2) / 64;
  int kc = 0, kc2 = 2;
  for (int t = 0; t < NT; ++t) {
    if (t < NT - 1) {
      asm volatile("s_waitcnt vmcnt(2)" ::: "memory");
    } else {
      asm volatile("s_waitcnt vmcnt(0)" ::: "memory");
    }
    __builtin_amdgcn_s_barrier();
    if (t + 1 < NT) STAGE_V((t + 1) & 1, (t + 1) * 64);
    if (t + 2 < NT) STAGE_K(kc2, (t + 2) * 64);
    char* cbK = pb + kc * 8192;
    char* cbV = pb + 24576 + (t & 1) * 8192;
    kc = (kc == 2) ? 0 : kc + 1;
    kc2 = (kc2 == 2) ? 0 : kc2 + 1;

    f32x16 st0 = {}, st1 = {};
    __builtin_amdgcn_s_setprio(1);
#pragma unroll
    for (int s = 0; s < 4; ++s) {
      bf16x8 kf0 = *(const bf16x8*)(cbK + l31 * 128 + ((s * 32 + cbase) ^ sw));
      bf16x8 kf1 = *(const bf16x8*)(cbK + 4096 + l31 * 128 + ((s * 32 + cbase) ^ sw));
      st0 = mfma32(kf0, qf[s], st0);
      st1 = mfma32(kf1, qf[s], st1);
    }
    __builtin_amdgcn_s_setprio(0);

    float p[32];
#pragma unroll
    for (int r = 0; r < 16; ++r) p[r] = __builtin_amdgcn_exp2f(fmaf(st0[r], sc, -FOFF));
#pragma unroll
    for (int r = 0; r < 16; ++r) p[16 + r] = __builtin_amdgcn_exp2f(fmaf(st1[r], sc, -FOFF));

    u32 P32[16];
#pragma unroll
    for (int i = 0; i < 16; ++i) {
      bf16 lo = tobf(p[2 * i]), hi = tobf(p[2 * i + 1]);
      unsigned short ul, uh;
      __builtin_memcpy(&ul, &lo, 2);
      __builtin_memcpy(&uh, &hi, 2);
      P32[i] = (u32)ul | ((u32)uh << 16);
    }

#if HAVE_DOT2
#pragma unroll
    for (int i = 0; i < 16; i += 4) {
      sacc0 = __builtin_amdgcn_fdot2_f32_bf16(__builtin_bit_cast(bf16x2, P32[i]), ones2, sacc0, false);
      sacc1 = __builtin_amdgcn_fdot2_f32_bf16(__builtin_bit_cast(bf16x2, P32[i + 1]), ones2, sacc1, false);
      sacc2 = __builtin_amdgcn_fdot2_f32_bf16(__builtin_bit_cast(bf16x2, P32[i + 2]), ones2, sacc2, false);
      sacc3 = __builtin_amdgcn_fdot2_f32_bf16(__builtin_bit_cast(bf16x2, P32[i + 3]), ones2, sacc3, false);
    }
#else
    {
      float sm[16];
#pragma unroll
      for (int i = 0; i < 16; ++i) {
        u32 ulo = P32[i] << 16, uhi = P32[i] & 0xffff0000u;
        float flo, fhi;
        __builtin_memcpy(&flo, &ulo, 4);
        __builtin_memcpy(&fhi, &uhi, 4);
        sm[i] = flo + fhi;
      }
#pragma unroll
      for (int off = 8; off > 0; off >>= 1)
#pragma unroll
        for (int r = 0; r < off; ++r) sm[r] += sm[r + off];
      ssum_run += sm[0];
    }
#endif

#if !HAVE_PLSWAP
    const int evens[8] = {0, 1, 4, 5, 8, 9, 12, 13};
    const int odds[8] = {2, 3, 6, 7, 10, 11, 14, 15};
    u32 recv[8];
#pragma unroll
    for (int j = 0; j < 8; ++j) {
      u32 sv = h5 ? P32[evens[j]] : P32[odds[j]];
      recv[j] = (u32)__shfl_xor((int)sv, 32, 64);
    }
#endif

    __builtin_amdgcn_s_setprio(1);
#pragma unroll
    for (int s2 = 0; s2 < 4; ++s2) {
      int x0 = ((s2 >> 1) << 3) + ((s2 & 1) << 2);  // 0,4,8,12
#if HAVE_PLSWAP
      u32x2 r02 = __builtin_amdgcn_permlane32_swap(P32[x0], P32[x0 + 2], false, false);
      u32x2 r13 = __builtin_amdgcn_permlane32_swap(P32[x0 + 1], P32[x0 + 3], false, false);
      u32x4 wv4 = {r02.x, r13.x, r02.y, r13.y};
#else
      u32 w0 = h5 ? recv[2 * s2] : P32[x0];
      u32 w1 = h5 ? recv[2 * s2 + 1] : P32[x0 + 1];
      u32 w2 = h5 ? P32[x0 + 2] : recv[2 * s2];
      u32 w3 = h5 ? P32[x0 + 3] : recv[2 * s2 + 1];
      u32x4 wv4 = {w0, w1, w2, w3};
#endif
      bf16x8 pfr = __builtin_bit_cast(bf16x8, wv4);
      bf16x8 vf0 = *(const bf16x8*)(cbV + l31 * 128 + ((s2 * 32 + cbase) ^ sw));
      bf16x8 vf1 = *(const bf16x8*)(cbV + 4096 + l31 * 128 + ((s2 * 32 + cbase) ^ sw));
      acc0 = mfma32(vf0, pfr, acc0);
      acc1 = mfma32(vf1, pfr, acc1);
    }
    __builtin_amdgcn_s_setprio(0);
  }

#if HAVE_DOT2
  float ssum = (sacc0 + sacc1) + (sacc2 + sacc3);
#else
  float ssum = ssum_run;
#endif

  __syncthreads();
  float* cacc = (float*)&lds[0][0];
  float* csum = (float*)(&lds[0][0] + 36864);
  int slot = (wsub * 64 + lane) * 36;
  if (pipe == 1) {
#pragma unroll
    for (int r = 0; r < 16; r += 4) {
      *(f32x4*)(cacc + slot + r) = f32x4{acc0[r], acc0[r + 1], acc0[r + 2], acc0[r + 3]};
      *(f32x4*)(cacc + slot + 16 + r) = f32x4{acc1[r], acc1[r + 1], acc1[r + 2], acc1[r + 3]};
    }
    csum[wsub * 64 + lane] = ssum;
  }
  __syncthreads();
  if (pipe == 0) {
#pragma unroll
    for (int r = 0; r < 16; r += 4) {
      f32x4 v0 = *(const f32x4*)(cacc + slot + r);
      f32x4 v1 = *(const f32x4*)(cacc + slot + 16 + r);
#pragma unroll
      for (int j = 0; j < 4; ++j) { acc0[r + j] += v0[j]; acc1[r + j] += v1[j]; }
    }
    ssum += csum[wsub * 64 + lane];
    ssum += __shfl_xor(ssum, 32, 64);
    float inv = 1.0f / ssum;
    size_t tok = (size_t)(b * SEQ + q0 + l31);
#pragma unroll
    for (int a = 0; a < 4; ++a) {
      bf16x4 ov0, ov1;
#pragma unroll
      for (int j = 0; j < 4; ++j) {
        ov0[j] = tobf(acc0[4 * a + j] * inv);
        ov1[j] = tobf(acc1[4 * a + j] * inv);
      }
      *(bf16x4*)(AO + tok * (NH * HD) + h * 64 + 8 * a + 4 * h5) = ov0;
      *(bf16x4*)(AO + tok * (NH * HD) + h * 64 + 32 + 8 * a + 4 * h5) = ov1;
    }
  }
#undef STAGE_K
#undef STAGE_V
}

// ---------------- launcher ----------------

extern "C" void kernel_launch(void* const* d_in, const int* in_sizes, int n_in,
                              void* d_out, int out_size, void* d_ws, size_t ws_size,
                              hipStream_t stream) {
  const float* hs = (const float*)d_in[0];
  const float* wqkv = (const float*)d_in[1];
  const float* wout = (const float*)d_in[2];
  const float* bout = (const float*)d_in[3];
  char* ws = (char*)d_ws;
  bf16* Xb = (bf16*)(ws + OXB);
  bf16* Wqkt = (bf16*)(ws + OWQ);
  bf16* Woutt = (bf16*)(ws + OWO);
  float* cs = (float*)(ws + OCS);
  bf16* Qr = (bf16*)(ws + OQR);
  bf16* Kr = (bf16*)(ws + OKR);
  bf16* Vt = (bf16*)(ws + OVT);
  bf16* AO = (bf16*)(ws + OAO);

  k_prep<<<7424, 256, 0, stream>>>(hs, wqkv, cs, Xb, Wqkt);
  k_gemm1f<<<(MTOK / 128) * (QKV3 / 128) + 1024, 256, 0, stream>>>(Xb, Wqkt, cs, wout, Woutt, Qr, Kr, Vt);
  k_attn<<<BATCH * NH * (SEQ / 128), 512, 0, stream>>>(Qr, Kr, Vt, AO);
  k_gemm2<<<(MTOK / 64) * (DMODEL / 128), 256, 0, stream>>>(AO, Woutt, (float*)d_out, bout, MTOK, DMODEL, DMODEL);
}